// Round 10
// baseline (436.990 us; speedup 1.0000x reference)
//
#include <hip/hip_runtime.h>
#include <hip/hip_bf16.h>

// GAT-GAE forward: 2x GATConv + normalize + MLP decoder. fp32 I/O, int32 edges.
// Round 10: 15 -> 8 graph nodes. ew1 fused into fill; ew2 fused into agg2;
// {w1f,w2f,deg} one block-ranged dispatch; {lookback-scan, gemm1} one dispatch
// (scan blocks first; 196 chunks co-resident -> no deadlock). agg1 gather
// batch deepened to 16.

#define IN_DIM   128
#define C1       256   // HEADS*HID
#define HEADS    4
#define HID      64
#define OUT_DIM  64

typedef __attribute__((ext_vector_type(8))) short short8;
typedef __attribute__((ext_vector_type(4))) float f32x4;

__device__ __forceinline__ float lrelu(float x) { return x > 0.f ? x : 0.2f * x; }
__device__ __forceinline__ float elu1(float x)  { return x > 0.f ? x : (__expf(x) - 1.f); }
__device__ __forceinline__ float expc(float x)  { return __expf(fminf(x, 60.f)); }
__device__ __forceinline__ float bfu(unsigned int u) {
    union { unsigned int i; float f; } c; c.i = u << 16; return c.f;
}
__device__ __forceinline__ unsigned short pk(float f) {
    union { float f; unsigned int i; } c; c.f = f;
    return (unsigned short)((c.i + 0x7fffu + ((c.i >> 16) & 1u)) >> 16);
}

// ========== stage1: w1f (16 blocks) | w2f (8 blocks) | deg (eblk blocks) =====
__global__ __launch_bounds__(256) void stage1_k(
    const float* __restrict__ W1, const float* __restrict__ W2,
    const int* __restrict__ ei, int E, int Etot,
    unsigned short* __restrict__ W1f, unsigned short* __restrict__ W2f,
    int* __restrict__ rowptr)
{
    const int b = blockIdx.x, t = threadIdx.x;
    if (b < 16) {            // W1 [128][256] -> B-fragment order
        const int idx = b * 256 + t;         // 4096 lane-entries
        const int lane = idx & 63, e = idx >> 6;
        const int nt = e >> 2, kc = e & 3, q = lane >> 4, c = lane & 15;
        unsigned short tmp[8];
        #pragma unroll
        for (int j = 0; j < 8; ++j)
            tmp[j] = pk(W1[(kc * 32 + q * 8 + j) * 256 + nt * 16 + c]);
        ushort4* dst = (ushort4*)(W1f + (size_t)idx * 8);
        dst[0] = make_ushort4(tmp[0], tmp[1], tmp[2], tmp[3]);
        dst[1] = make_ushort4(tmp[4], tmp[5], tmp[6], tmp[7]);
    } else if (b < 24) {     // W2 [256][64] -> B-fragment order
        const int idx = (b - 16) * 256 + t;  // 2048 lane-entries
        const int lane = idx & 63, e = idx >> 6;
        const int nt = e >> 3, kc = e & 7, q = lane >> 4, c = lane & 15;
        unsigned short tmp[8];
        #pragma unroll
        for (int j = 0; j < 8; ++j)
            tmp[j] = pk(W2[(kc * 32 + q * 8 + j) * 64 + nt * 16 + c]);
        ushort4* dst = (ushort4*)(W2f + (size_t)idx * 8);
        dst[0] = make_ushort4(tmp[0], tmp[1], tmp[2], tmp[3]);
        dst[1] = make_ushort4(tmp[4], tmp[5], tmp[6], tmp[7]);
    } else {                 // degree count
        const int e = (b - 24) * 256 + t;
        if (e < Etot) {
            const int d = (e < E) ? ei[E + e] : e - E;
            atomicAdd(&rowptr[1 + d], 1);
        }
    }
}

__device__ __forceinline__ int blk_incl_scan(int v, int t) {
    __shared__ int wsum[4];
    const int lane = t & 63, wid = t >> 6;
    int s = v;
    #pragma unroll
    for (int off = 1; off < 64; off <<= 1) {
        const int u = __shfl_up(s, off, 64);
        if (lane >= off) s += u;
    }
    if (lane == 63) wsum[wid] = s;
    __syncthreads();
    int add = 0;
    #pragma unroll
    for (int k = 0; k < 4; ++k) if (k < wid) add += wsum[k];
    __syncthreads();
    return s + add;
}

// ===== stage2: lookback scan (SC blocks, FIRST) | gemm1 MFMA (mblk blocks) ===
__global__ __launch_bounds__(256) void stage2_k(
    int* __restrict__ rowptr, int* __restrict__ cursor, int* __restrict__ status,
    const float* __restrict__ x, const unsigned short* __restrict__ W1f,
    const float* __restrict__ as1, const float* __restrict__ ad1,
    unsigned short* __restrict__ h1b, float* __restrict__ a_s1,
    float* __restrict__ a_d1, int N, int SC)
{
    const int t = threadIdx.x;
    if ((int)blockIdx.x < SC) {   // ---- scan role (decoupled lookback) ----
        const int chunk = blockIdx.x;
        const int i = chunk * 256 + t;
        const int v = (i < N) ? rowptr[1 + i] : 0;
        const int inc = blk_incl_scan(v, t);
        __shared__ int sbase;
        if (t == 255) {
            int base = 0;
            if (chunk > 0) {
                volatile int* st = (volatile int*)status;
                int s;
                while ((s = st[chunk - 1]) == 0) { }
                base = s - 1;
            }
            ((volatile int*)status)[chunk] = base + inc + 1;  // inc@255 = total
            sbase = base;
        }
        __syncthreads();
        const int base = sbase;
        if (i < N) {
            rowptr[1 + i] = base + inc;
            cursor[i]     = base + inc - v;
        }
        return;
    }
    // ---- gemm1 role: h1 = x @ W1 (bf16 table) + logits ----
    __shared__ short lds[64 * 264];   // stage: [row][136]; epilogue: [row][264]
    const int bb = blockIdx.x - SC;
    const int w = t >> 6, l = t & 63;
    const int q = l >> 4, c = l & 15;
    const int n0 = bb * 64;
    for (int i = t; i < 64 * 32; i += 256) {
        const int r = i >> 5, k4 = (i & 31) * 4;
        const int rn = min(n0 + r, N - 1);
        const float4 v = *(const float4*)&x[(size_t)rn * IN_DIM + k4];
        *(ushort4*)&lds[r * 136 + k4] =
            make_ushort4(pk(v.x), pk(v.y), pk(v.z), pk(v.w));
    }
    __syncthreads();
    short8 afr[4];
    const int arow = 16 * w + c;
    #pragma unroll
    for (int kc = 0; kc < 4; ++kc)
        afr[kc] = *(const short8*)&lds[arow * 136 + kc * 32 + q * 8];
    f32x4 acc[16];
    #pragma unroll
    for (int nt = 0; nt < 16; ++nt) acc[nt] = (f32x4){0.f, 0.f, 0.f, 0.f};
    #pragma unroll
    for (int nt = 0; nt < 16; ++nt) {
        #pragma unroll
        for (int kc = 0; kc < 4; ++kc) {
            const short8 bfr =
                *(const short8*)(W1f + ((size_t)(nt * 4 + kc) * 64 + l) * 8);
            acc[nt] = __builtin_amdgcn_mfma_f32_16x16x32_bf16(afr[kc], bfr,
                                                              acc[nt], 0, 0, 0);
        }
    }
    #pragma unroll
    for (int h = 0; h < 4; ++h) {
        float vsr[4] = {0.f, 0.f, 0.f, 0.f}, vdr[4] = {0.f, 0.f, 0.f, 0.f};
        #pragma unroll
        for (int n4 = 0; n4 < 4; ++n4) {
            const int nt = h * 4 + n4;
            const float sa = as1[nt * 16 + c], da = ad1[nt * 16 + c];
            #pragma unroll
            for (int r = 0; r < 4; ++r) {
                vsr[r] += acc[nt][r] * sa;
                vdr[r] += acc[nt][r] * da;
            }
        }
        #pragma unroll
        for (int r = 0; r < 4; ++r) {
            #pragma unroll
            for (int off = 1; off < 16; off <<= 1) {
                vsr[r] += __shfl_xor(vsr[r], off, 64);
                vdr[r] += __shfl_xor(vdr[r], off, 64);
            }
            const int node = n0 + 16 * w + q * 4 + r;
            if (c == 0 && node < N) {
                a_s1[node * 4 + h] = vsr[r];
                a_d1[node * 4 + h] = vdr[r];
            }
        }
    }
    __syncthreads();
    #pragma unroll
    for (int nt = 0; nt < 16; ++nt)
        #pragma unroll
        for (int r = 0; r < 4; ++r)
            lds[(16 * w + q * 4 + r) * 264 + nt * 16 + c] = (short)pk(acc[nt][r]);
    __syncthreads();
    for (int i = t; i < 64 * 32; i += 256) {
        const int r = i >> 5, ch = (i & 31) * 8;
        const int node = n0 + r;
        if (node < N)
            *(short8*)&h1b[(size_t)node * C1 + ch] =
                *(const short8*)&lds[r * 264 + ch];
    }
}

// ====== fill CSR + layer-1 edge weights (fused; row[] eliminated) ======
__global__ void fill_ew1_k(const int* __restrict__ ei, int E, int Etot,
                           int* __restrict__ cursor, int* __restrict__ col,
                           const float* __restrict__ a_s1,
                           const float* __restrict__ a_d1,
                           float* __restrict__ ew1)
{
    const int e = blockIdx.x * blockDim.x + threadIdx.x;
    if (e >= Etot) return;
    int s, d;
    if (e < E) { s = ei[e]; d = ei[E + e]; } else { s = d = e - E; }
    const int pos = atomicAdd(&cursor[d], 1);
    col[pos] = s;
    const float4 sv = *(const float4*)&a_s1[s * 4];
    const float4 dv = *(const float4*)&a_d1[d * 4];
    float4 w;
    w.x = expc(lrelu(sv.x + dv.x));
    w.y = expc(lrelu(sv.y + dv.y));
    w.z = expc(lrelu(sv.z + dv.z));
    w.w = expc(lrelu(sv.w + dv.w));
    *(float4*)&ew1[(size_t)pos * 4] = w;
}

// ====== Layer-1 aggregate: 1 wave/node, lane = 4 ch; 16-deep batched ======
__global__ __launch_bounds__(256) void agg1_k(
    const int* __restrict__ rowptr, const int* __restrict__ col,
    const float* __restrict__ ew1, const unsigned short* __restrict__ h1b,
    const float* __restrict__ b1, unsigned short* __restrict__ hxb, int N)
{
    const int t = threadIdx.x, w = t >> 6, l = t & 63;
    const int n = blockIdx.x * 4 + w;
    if (n >= N) return;
    const int beg = rowptr[n], end = rowptr[n + 1];
    const int head = l >> 4;
    float a0 = 0.f, a1 = 0.f, a2 = 0.f, a3 = 0.f, wsum = 0.f;
    for (int t0 = beg; t0 < end; t0 += 64) {
        const int m = min(64, end - t0);
        const int p = t0 + l;
        const int scol = (p < end) ? col[p] : 0;
        for (int g = 0; g < m; g += 16) {
            const int pe = t0 + g + (l & 15);
            const float wst = (pe < end) ? ew1[(size_t)pe * 4 + head] : 0.f;
            const int mm = min(16, m - g);
            ushort4 hv[16]; float wu[16];
            #pragma unroll
            for (int u = 0; u < 16; ++u) {
                if (u < mm) {
                    const int su = __shfl(scol, g + u, 64);
                    wu[u] = __shfl(wst, (l & 48) + u, 64);
                    hv[u] = *(const ushort4*)(h1b + (size_t)su * C1 + 4 * l);
                } else {
                    wu[u] = 0.f;
                    hv[u] = make_ushort4(0, 0, 0, 0);
                }
            }
            #pragma unroll
            for (int u = 0; u < 16; ++u) {
                a0 = fmaf(bfu(hv[u].x), wu[u], a0);
                a1 = fmaf(bfu(hv[u].y), wu[u], a1);
                a2 = fmaf(bfu(hv[u].z), wu[u], a2);
                a3 = fmaf(bfu(hv[u].w), wu[u], a3);
                wsum += wu[u];
            }
        }
    }
    const float4 bb = *(const float4*)&b1[4 * l];
    const float inv = 1.f / (wsum + 1e-16f);
    ushort4 o;
    o.x = pk(elu1(a0 * inv + bb.x));
    o.y = pk(elu1(a1 * inv + bb.y));
    o.z = pk(elu1(a2 * inv + bb.z));
    o.w = pk(elu1(a3 * inv + bb.w));
    *(ushort4*)&hxb[(size_t)n * C1 + 4 * l] = o;
}

// ============ Layer-2 GEMM (MFMA): h2 = h @ W2 (bf16) + logits ==============
__global__ __launch_bounds__(256) void gemm2_k(
    const unsigned short* __restrict__ hxb, const unsigned short* __restrict__ W2f,
    const float* __restrict__ as2, const float* __restrict__ ad2,
    unsigned short* __restrict__ h2b, float* __restrict__ a_s2,
    float* __restrict__ a_d2, int N)
{
    __shared__ short lds[64 * 264];
    const int t = threadIdx.x, w = t >> 6, l = t & 63;
    const int q = l >> 4, c = l & 15;
    const int n0 = blockIdx.x * 64;
    for (int i = t; i < 64 * 32; i += 256) {
        const int r = i >> 5, ch = (i & 31) * 8;
        const int rn = min(n0 + r, N - 1);
        *(short8*)&lds[r * 264 + ch] =
            *(const short8*)&hxb[(size_t)rn * C1 + ch];
    }
    __syncthreads();
    short8 afr[8];
    const int arow = 16 * w + c;
    #pragma unroll
    for (int kc = 0; kc < 8; ++kc)
        afr[kc] = *(const short8*)&lds[arow * 264 + kc * 32 + q * 8];
    f32x4 acc[4];
    #pragma unroll
    for (int nt = 0; nt < 4; ++nt) acc[nt] = (f32x4){0.f, 0.f, 0.f, 0.f};
    #pragma unroll
    for (int nt = 0; nt < 4; ++nt) {
        #pragma unroll
        for (int kc = 0; kc < 8; ++kc) {
            const short8 bfr =
                *(const short8*)(W2f + ((size_t)(nt * 8 + kc) * 64 + l) * 8);
            acc[nt] = __builtin_amdgcn_mfma_f32_16x16x32_bf16(afr[kc], bfr,
                                                              acc[nt], 0, 0, 0);
        }
    }
    {
        float vsr[4] = {0.f, 0.f, 0.f, 0.f}, vdr[4] = {0.f, 0.f, 0.f, 0.f};
        #pragma unroll
        for (int nt = 0; nt < 4; ++nt) {
            const float sa = as2[nt * 16 + c], da = ad2[nt * 16 + c];
            #pragma unroll
            for (int r = 0; r < 4; ++r) {
                vsr[r] += acc[nt][r] * sa;
                vdr[r] += acc[nt][r] * da;
            }
        }
        #pragma unroll
        for (int r = 0; r < 4; ++r) {
            #pragma unroll
            for (int off = 1; off < 16; off <<= 1) {
                vsr[r] += __shfl_xor(vsr[r], off, 64);
                vdr[r] += __shfl_xor(vdr[r], off, 64);
            }
            const int node = n0 + 16 * w + q * 4 + r;
            if (c == 0 && node < N) {
                a_s2[node] = vsr[r];
                a_d2[node] = vdr[r];
            }
        }
    }
    __syncthreads();
    #pragma unroll
    for (int nt = 0; nt < 4; ++nt)
        #pragma unroll
        for (int r = 0; r < 4; ++r)
            lds[(16 * w + q * 4 + r) * 72 + nt * 16 + c] = (short)pk(acc[nt][r]);
    __syncthreads();
    for (int i = t; i < 64 * 8; i += 256) {
        const int r = i >> 3, ch = (i & 7) * 8;
        const int node = n0 + r;
        if (node < N)
            *(short8*)&h2b[(size_t)node * OUT_DIM + ch] =
                *(const short8*)&lds[r * 72 + ch];
    }
}

// == Layer-2 aggregate + fused edge weights + bias + L2-normalize -> z ==
__global__ __launch_bounds__(256) void agg2_k(
    const int* __restrict__ rowptr, const int* __restrict__ col,
    const float* __restrict__ a_s2, const float* __restrict__ a_d2,
    const unsigned short* __restrict__ h2b, const float* __restrict__ b2,
    float* __restrict__ zout, int N)
{
    const int t = threadIdx.x, w = t >> 6, l = t & 63;
    const int n = blockIdx.x * 4 + w;
    if (n >= N) return;
    const int beg = rowptr[n], end = rowptr[n + 1];
    const int half = l >> 5, c2 = l & 31;     // lane owns ch 2*c2, 2*c2+1
    const float ad2n = a_d2[n];
    float a0 = 0.f, a1 = 0.f, wsum = 0.f;
    for (int t0 = beg; t0 < end; t0 += 64) {
        const int m = min(64, end - t0);
        const int p = t0 + l;
        const int scol = (p < end) ? col[p] : 0;
        float wv = 0.f;
        if (p < end) wv = expc(lrelu(a_s2[scol] + ad2n));   // fused ew2
        const int pairs = (m + 1) >> 1;
        for (int j0 = 0; j0 < pairs; j0 += 8) {
            unsigned int hv[8]; float wu[8];
            #pragma unroll
            for (int u = 0; u < 8; ++u) {
                const int e = 2 * (j0 + u) + half;        // <= 63 always
                const int su = __shfl(scol, e, 64);
                wu[u] = __shfl(wv, e, 64);
                hv[u] = *(const unsigned int*)(h2b + (size_t)su * OUT_DIM + 2 * c2);
            }
            #pragma unroll
            for (int u = 0; u < 8; ++u) {
                a0 = fmaf(bfu(hv[u] & 0xffffu), wu[u], a0);
                a1 = fmaf(bfu(hv[u] >> 16), wu[u], a1);
                wsum += wu[u];
            }
        }
    }
    a0   += __shfl_xor(a0, 32, 64);
    a1   += __shfl_xor(a1, 32, 64);
    wsum += __shfl_xor(wsum, 32, 64);
    const float inv = 1.f / (wsum + 1e-16f);
    float z0 = a0 * inv + b2[2 * c2];
    float z1 = a1 * inv + b2[2 * c2 + 1];
    float sq = z0 * z0 + z1 * z1;
    #pragma unroll
    for (int off = 1; off < 32; off <<= 1) sq += __shfl_xor(sq, off, 64);
    const float rn = 1.f / fmaxf(sqrtf(sq), 1e-12f);
    if (l < 32) {
        float2 o; o.x = z0 * rn; o.y = z1 * rn;
        *(float2*)&zout[(size_t)n * OUT_DIM + 2 * c2] = o;
    }
}

// ================= Decoder: x_hat = elu(z@dW1+db1)@dW2+db2 =================
__global__ __launch_bounds__(256) void dec_k(
    const float* __restrict__ z,
    const float* __restrict__ dW1, const float* __restrict__ db1,
    const float* __restrict__ dW2, const float* __restrict__ db2,
    float* __restrict__ xhat, int N)
{
    __shared__ float zs[32 * 64];
    __shared__ float ts[32 * 64];
    const int t = threadIdx.x;
    const int n0 = blockIdx.x * 32;
    for (int i = t; i < 32 * 64; i += 256) {
        const int nb_l = i >> 6, k = i & 63;
        const int n = min(n0 + nb_l, N - 1);
        zs[(nb_l >> 3) * 512 + k * 8 + (nb_l & 7)] = z[(size_t)n * OUT_DIM + k];
    }
    __syncthreads();
    const int w = t >> 6, l = t & 63;
    const float* zw = zs + w * 512;
    float* tw = ts + w * 512;
    float acc[8] = {0.f, 0.f, 0.f, 0.f, 0.f, 0.f, 0.f, 0.f};
    #pragma unroll 4
    for (int k = 0; k < 64; ++k) {
        const float wv = dW1[k * HID + l];
        const float4 xa = *(const float4*)&zw[k * 8];
        const float4 xb = *(const float4*)&zw[k * 8 + 4];
        acc[0] += xa.x * wv; acc[1] += xa.y * wv;
        acc[2] += xa.z * wv; acc[3] += xa.w * wv;
        acc[4] += xb.x * wv; acc[5] += xb.y * wv;
        acc[6] += xb.z * wv; acc[7] += xb.w * wv;
    }
    const float bb = db1[l];
    #pragma unroll
    for (int nb = 0; nb < 8; ++nb) tw[l * 8 + nb] = elu1(acc[nb] + bb);
    __syncthreads();
    float a0[8] = {0.f, 0.f, 0.f, 0.f, 0.f, 0.f, 0.f, 0.f};
    float a1[8] = {0.f, 0.f, 0.f, 0.f, 0.f, 0.f, 0.f, 0.f};
    #pragma unroll 2
    for (int k = 0; k < 64; ++k) {
        const float w0 = dW2[k * IN_DIM + l];
        const float w1 = dW2[k * IN_DIM + 64 + l];
        const float4 xa = *(const float4*)&tw[k * 8];
        const float4 xb = *(const float4*)&tw[k * 8 + 4];
        const float xv[8] = {xa.x, xa.y, xa.z, xa.w, xb.x, xb.y, xb.z, xb.w};
        #pragma unroll
        for (int nb = 0; nb < 8; ++nb) {
            a0[nb] += xv[nb] * w0;
            a1[nb] += xv[nb] * w1;
        }
    }
    const float bb0 = db2[l], bb1 = db2[64 + l];
    #pragma unroll
    for (int nb = 0; nb < 8; ++nb) {
        const int n = n0 + w * 8 + nb;
        if (n >= N) break;
        xhat[(size_t)n * IN_DIM + l]      = a0[nb] + bb0;
        xhat[(size_t)n * IN_DIM + 64 + l] = a1[nb] + bb1;
    }
}

extern "C" void kernel_launch(void* const* d_in, const int* in_sizes, int n_in,
                              void* d_out, int out_size, void* d_ws, size_t ws_size,
                              hipStream_t stream)
{
    const float* x   = (const float*)d_in[0];
    const int*   ei  = (const int*)d_in[1];
    const float* W1  = (const float*)d_in[2];
    const float* as1 = (const float*)d_in[3];
    const float* ad1 = (const float*)d_in[4];
    const float* b1  = (const float*)d_in[5];
    const float* W2  = (const float*)d_in[6];
    const float* as2 = (const float*)d_in[7];
    const float* ad2 = (const float*)d_in[8];
    const float* b2  = (const float*)d_in[9];
    const float* dW1 = (const float*)d_in[10];
    const float* db1 = (const float*)d_in[11];
    const float* dW2 = (const float*)d_in[12];
    const float* db2 = (const float*)d_in[13];

    const int N    = in_sizes[0] / IN_DIM;
    const int E    = in_sizes[1] / 2;
    const int Etot = E + N;
    const int SC   = (N + 255) / 256;

    // ---- 64B-aligned workspace carving ----
    char* base = (char*)d_ws;
    size_t off = 0;
    auto take = [&](size_t bytes) -> char* {
        off = (off + 63) & ~(size_t)63;
        char* p = base + off;
        off += bytes;
        return p;
    };
    unsigned short* hxb = (unsigned short*)take((size_t)N * C1 * 2);
    float* a_s1 = (float*)take((size_t)N * HEADS * 4);
    float* a_d1 = (float*)take((size_t)N * HEADS * 4);
    float* a_s2 = (float*)take((size_t)N * 4);
    float* a_d2 = (float*)take((size_t)N * 4);
    float* ew1  = (float*)take((size_t)Etot * HEADS * 4);
    unsigned short* h1b = (unsigned short*)take((size_t)N * C1 * 2);
    unsigned short* h2b = (unsigned short*)take((size_t)N * OUT_DIM * 2);
    int* rowptr = (int*)take((size_t)(N + 1) * 4);
    int* status = (int*)take((size_t)SC * 4);     // adjacent to rowptr (zeroed)
    int* cursor = (int*)take((size_t)N * 4);
    int* col    = (int*)take((size_t)Etot * 4);
    unsigned short* W1f = (unsigned short*)take(64 * 64 * 8 * 2);
    unsigned short* W2f = (unsigned short*)take(32 * 64 * 8 * 2);
    if (off > ws_size) return;   // loud failure signature (absmax ~0.543)

    // zero rowptr + status in one memset (they are consecutive allocations)
    const size_t zspan = (size_t)((char*)(status + SC) - (char*)rowptr);
    hipMemsetAsync(rowptr, 0, zspan, stream);

    const int eblk = (Etot + 255) / 256;
    const int mblk = (N + 63) / 64;
    stage1_k<<<24 + eblk, 256, 0, stream>>>(W1, W2, ei, E, Etot, W1f, W2f, rowptr);
    stage2_k<<<SC + mblk, 256, 0, stream>>>(rowptr, cursor, status,
                                            x, W1f, as1, ad1, h1b, a_s1, a_d1,
                                            N, SC);
    fill_ew1_k<<<eblk, 256, 0, stream>>>(ei, E, Etot, cursor, col, a_s1, a_d1, ew1);
    agg1_k <<<(N + 3) / 4, 256, 0, stream>>>(rowptr, col, ew1, h1b, b1, hxb, N);
    gemm2_k<<<mblk, 256, 0, stream>>>(hxb, W2f, as2, ad2, h2b, a_s2, a_d2, N);
    agg2_k <<<(N + 3) / 4, 256, 0, stream>>>(rowptr, col, a_s2, a_d2, h2b, b2,
                                             (float*)d_out, N);
    dec_k  <<<(N + 31) / 32, 256, 0, stream>>>((const float*)d_out, dW1, db1,
                                               dW2, db2,
                                               (float*)d_out + (size_t)N * OUT_DIM, N);
}